// Round 2
// baseline (160.695 us; speedup 1.0000x reference)
//
#include <hip/hip_runtime.h>

#define GRID_NX 4096
#define GRID_NY 4096
#define PPT 4   // points per thread

// Bilinear interpolation on a uniform unit grid (xs = ys = arange).
// searchsorted(arange, x, 'left') == ceil(x) for f32 x in [0, 4095],
// clipped to [1, 4095]. Grid spacing is exactly 1.0f so wx = x - x0.
//
// 4 points/thread: all 16 z-gathers issue back-to-back (independent),
// quadrupling outstanding misses per wave to hide L3-hit latency.
__global__ __launch_bounds__(256) void bilerp_kernel4(
    const float4* __restrict__ pts4,   // pts viewed as float4 (2 points each)
    const float* __restrict__ zs,
    float4* __restrict__ out4,
    int n4)                            // number of float4-output groups (= n/4)
{
    int t = blockIdx.x * blockDim.x + threadIdx.x;
    if (t >= n4) return;

    // Load 4 points = 32 B contiguous per lane (two dwordx4).
    float4 a = pts4[2 * t];       // (x0,y0,x1,y1)
    float4 b = pts4[2 * t + 1];   // (x2,y2,x3,y3)

    float x[PPT] = {a.x, a.z, b.x, b.z};
    float y[PPT] = {a.y, a.w, b.y, b.w};

    float z00[PPT], z01[PPT], z10[PPT], z11[PPT];
    float wx[PPT], wy[PPT];

#pragma unroll
    for (int k = 0; k < PPT; ++k) {
        int ix = (int)ceilf(x[k]);
        int iy = (int)ceilf(y[k]);
        ix = min(max(ix, 1), GRID_NX - 1);
        iy = min(max(iy, 1), GRID_NY - 1);
        wx[k] = x[k] - (float)(ix - 1);
        wy[k] = y[k] - (float)(iy - 1);
        const float* base = zs + (size_t)(ix - 1) * GRID_NY + (iy - 1);
        z00[k] = base[0];
        z01[k] = base[1];
        z10[k] = base[GRID_NY];
        z11[k] = base[GRID_NY + 1];
    }

    float4 r;
    float* rp = &r.x;
#pragma unroll
    for (int k = 0; k < PPT; ++k) {
        float r0 = (1.0f - wy[k]) * z00[k] + wy[k] * z01[k];
        float r1 = (1.0f - wy[k]) * z10[k] + wy[k] * z11[k];
        rp[k] = (1.0f - wx[k]) * r0 + wx[k] * r1;
    }
    out4[t] = r;
}

extern "C" void kernel_launch(void* const* d_in, const int* in_sizes, int n_in,
                              void* d_out, int out_size, void* d_ws, size_t ws_size,
                              hipStream_t stream) {
    const float4* pts4 = (const float4*)d_in[0];  // N_POINTS x 2 f32
    const float* zs = (const float*)d_in[3];      // 4096 x 4096 f32
    float4* out4 = (float4*)d_out;

    int n = in_sizes[0] / 2;        // number of points (4194304, divisible by 4)
    int n4 = n / 4;
    int block = 256;
    int grid = (n4 + block - 1) / block;
    bilerp_kernel4<<<grid, block, 0, stream>>>(pts4, zs, out4, n4);
}

// Round 3
// 160.032 us; speedup vs baseline: 1.0041x; 1.0041x over previous
//
#include <hip/hip_runtime.h>

#define GRID_NX 4096
#define GRID_NY 4096
#define PPT 4   // points per thread

// Bilinear interpolation on a uniform unit grid (xs = ys = arange).
// searchsorted(arange, x, 'left') == ceil(x) for f32 x in [0, 4095],
// clipped to [1, 4095]. Grid spacing is exactly 1.0f so wx = x - x0.
//
// Key change vs round 2: fetch each adjacent (z_lo, z_hi) row pair with a
// single 8 B load (global_load_dwordx2) instead of two dword loads --
// halves vector-memory requests per point (4 -> 2) with identical cache-line
// footprint. Tests the request-throughput-bound hypothesis.
__global__ __launch_bounds__(256) void bilerp_kernel4b(
    const float4* __restrict__ pts4,   // pts viewed as float4 (2 points each)
    const float* __restrict__ zs,
    float4* __restrict__ out4,
    int n4)
{
    int t = blockIdx.x * blockDim.x + threadIdx.x;
    if (t >= n4) return;

    float4 a = pts4[2 * t];       // (x0,y0,x1,y1)
    float4 b = pts4[2 * t + 1];   // (x2,y2,x3,y3)

    float x[PPT] = {a.x, a.z, b.x, b.z};
    float y[PPT] = {a.y, a.w, b.y, b.w};

    float2 lo[PPT], hi[PPT];
    float wx[PPT], wy[PPT];

#pragma unroll
    for (int k = 0; k < PPT; ++k) {
        int ix = (int)ceilf(x[k]);
        int iy = (int)ceilf(y[k]);
        ix = min(max(ix, 1), GRID_NX - 1);
        iy = min(max(iy, 1), GRID_NY - 1);
        wx[k] = x[k] - (float)(ix - 1);
        wy[k] = y[k] - (float)(iy - 1);
        const float* base = zs + (size_t)(ix - 1) * GRID_NY + (iy - 1);
        // 8 B loads; dword-aligned is sufficient for dwordx2 on CDNA.
        lo[k] = *reinterpret_cast<const float2*>(base);
        hi[k] = *reinterpret_cast<const float2*>(base + GRID_NY);
    }

    float4 r;
    float* rp = &r.x;
#pragma unroll
    for (int k = 0; k < PPT; ++k) {
        float r0 = (1.0f - wy[k]) * lo[k].x + wy[k] * lo[k].y;
        float r1 = (1.0f - wy[k]) * hi[k].x + wy[k] * hi[k].y;
        rp[k] = (1.0f - wx[k]) * r0 + wx[k] * r1;
    }
    out4[t] = r;
}

extern "C" void kernel_launch(void* const* d_in, const int* in_sizes, int n_in,
                              void* d_out, int out_size, void* d_ws, size_t ws_size,
                              hipStream_t stream) {
    const float4* pts4 = (const float4*)d_in[0];  // N_POINTS x 2 f32
    const float* zs = (const float*)d_in[3];      // 4096 x 4096 f32
    float4* out4 = (float4*)d_out;

    int n = in_sizes[0] / 2;        // number of points (4194304, divisible by 4)
    int n4 = n / 4;
    int block = 256;
    int grid = (n4 + block - 1) / block;
    bilerp_kernel4b<<<grid, block, 0, stream>>>(pts4, zs, out4, n4);
}

// Round 4
// 116.331 us; speedup vs baseline: 1.3814x; 1.3757x over previous
//
#include <hip/hip_runtime.h>

#define GRID_NX 4096
#define GRID_NY 4096
#define PPT 4

// Round 4: two-pass scheme.
//
// Pass 1 (streaming): repack zs into a bf16 vertical-pair table
//   zp[i][j] = { bf16(zs[i][j]) , bf16(zs[i+1][j]) }   (one u32), i<4095.
// Pass 2 (gather): each point reads ONE 8-byte load at (ix-1, iy-1):
//   two u32s give (z00,z10) and (z01,z11). One random cache line per point
//   instead of two -> halves the line-fill traffic that bounds this kernel
//   (rounds 2-3 showed: not latency-, not instruction-bound; FETCH_SIZE
//   525 MB @ 3.44 TB/s is the wall).
//
// bf16 RNE on |z|<~5.6 adds <=~0.011 abs error; threshold is 8.6e-2.

__device__ __forceinline__ unsigned int bf16rn(float f) {
    unsigned int v = __builtin_bit_cast(unsigned int, f);
    return (v + 0x7fffu + ((v >> 16) & 1u)) >> 16;   // round-nearest-even
}

__global__ __launch_bounds__(256) void pack_kernel(
    const float* __restrict__ zs,
    unsigned int* __restrict__ zp)   // (GRID_NX-1) x GRID_NY u32
{
    int t = blockIdx.x * blockDim.x + threadIdx.x;   // one float4-column group
    const int groups_per_row = GRID_NY / 4;          // 1024
    int i = t / groups_per_row;
    int g = t % groups_per_row;
    if (i >= GRID_NX - 1) return;

    const float4 lo = *reinterpret_cast<const float4*>(zs + (size_t)i * GRID_NY + 4 * g);
    const float4 hi = *reinterpret_cast<const float4*>(zs + (size_t)(i + 1) * GRID_NY + 4 * g);

    uint4 r;
    r.x = bf16rn(lo.x) | (bf16rn(hi.x) << 16);
    r.y = bf16rn(lo.y) | (bf16rn(hi.y) << 16);
    r.z = bf16rn(lo.z) | (bf16rn(hi.z) << 16);
    r.w = bf16rn(lo.w) | (bf16rn(hi.w) << 16);
    *reinterpret_cast<uint4*>(zp + (size_t)i * GRID_NY + 4 * g) = r;
}

__device__ __forceinline__ float bf16lo_f(unsigned int u) {
    return __builtin_bit_cast(float, u << 16);
}
__device__ __forceinline__ float bf16hi_f(unsigned int u) {
    return __builtin_bit_cast(float, u & 0xffff0000u);
}

__global__ __launch_bounds__(256) void bilerp_packed(
    const float4* __restrict__ pts4,
    const unsigned int* __restrict__ zp,
    float4* __restrict__ out4,
    int n4)
{
    int t = blockIdx.x * blockDim.x + threadIdx.x;
    if (t >= n4) return;

    float4 a = pts4[2 * t];
    float4 b = pts4[2 * t + 1];
    float x[PPT] = {a.x, a.z, b.x, b.z};
    float y[PPT] = {a.y, a.w, b.y, b.w};

    uint2 q[PPT];
    float wx[PPT], wy[PPT];
#pragma unroll
    for (int k = 0; k < PPT; ++k) {
        int ix = (int)ceilf(x[k]);
        int iy = (int)ceilf(y[k]);
        ix = min(max(ix, 1), GRID_NX - 1);
        iy = min(max(iy, 1), GRID_NY - 1);
        wx[k] = x[k] - (float)(ix - 1);
        wy[k] = y[k] - (float)(iy - 1);
        // one 8B load: col iy-1 -> (z00,z10), col iy -> (z01,z11)
        q[k] = *reinterpret_cast<const uint2*>(zp + (size_t)(ix - 1) * GRID_NY + (iy - 1));
    }

    float4 r;
    float* rp = &r.x;
#pragma unroll
    for (int k = 0; k < PPT; ++k) {
        float z00 = bf16lo_f(q[k].x), z10 = bf16hi_f(q[k].x);
        float z01 = bf16lo_f(q[k].y), z11 = bf16hi_f(q[k].y);
        float r0 = (1.0f - wy[k]) * z00 + wy[k] * z01;
        float r1 = (1.0f - wy[k]) * z10 + wy[k] * z11;
        rp[k] = (1.0f - wx[k]) * r0 + wx[k] * r1;
    }
    out4[t] = r;
}

// Fallback (rounds 1-3 kernel) if workspace is too small for the table.
__global__ __launch_bounds__(256) void bilerp_direct(
    const float4* __restrict__ pts4,
    const float* __restrict__ zs,
    float4* __restrict__ out4,
    int n4)
{
    int t = blockIdx.x * blockDim.x + threadIdx.x;
    if (t >= n4) return;
    float4 a = pts4[2 * t];
    float4 b = pts4[2 * t + 1];
    float x[PPT] = {a.x, a.z, b.x, b.z};
    float y[PPT] = {a.y, a.w, b.y, b.w};
    float2 lo[PPT], hi[PPT];
    float wx[PPT], wy[PPT];
#pragma unroll
    for (int k = 0; k < PPT; ++k) {
        int ix = (int)ceilf(x[k]);
        int iy = (int)ceilf(y[k]);
        ix = min(max(ix, 1), GRID_NX - 1);
        iy = min(max(iy, 1), GRID_NY - 1);
        wx[k] = x[k] - (float)(ix - 1);
        wy[k] = y[k] - (float)(iy - 1);
        const float* base = zs + (size_t)(ix - 1) * GRID_NY + (iy - 1);
        lo[k] = *reinterpret_cast<const float2*>(base);
        hi[k] = *reinterpret_cast<const float2*>(base + GRID_NY);
    }
    float4 r;
    float* rp = &r.x;
#pragma unroll
    for (int k = 0; k < PPT; ++k) {
        float r0 = (1.0f - wy[k]) * lo[k].x + wy[k] * lo[k].y;
        float r1 = (1.0f - wy[k]) * hi[k].x + wy[k] * hi[k].y;
        rp[k] = (1.0f - wx[k]) * r0 + wx[k] * r1;
    }
    out4[t] = r;
}

extern "C" void kernel_launch(void* const* d_in, const int* in_sizes, int n_in,
                              void* d_out, int out_size, void* d_ws, size_t ws_size,
                              hipStream_t stream) {
    const float4* pts4 = (const float4*)d_in[0];
    const float* zs = (const float*)d_in[3];
    float4* out4 = (float4*)d_out;

    int n = in_sizes[0] / 2;
    int n4 = n / 4;
    int block = 256;
    int grid = (n4 + block - 1) / block;

    const size_t table_bytes = (size_t)(GRID_NX - 1) * GRID_NY * sizeof(unsigned int);
    if (ws_size >= table_bytes) {
        unsigned int* zp = (unsigned int*)d_ws;
        int pack_threads = (GRID_NX - 1) * (GRID_NY / 4);
        int pack_grid = (pack_threads + block - 1) / block;
        pack_kernel<<<pack_grid, block, 0, stream>>>(zs, zp);
        bilerp_packed<<<grid, block, 0, stream>>>(pts4, zp, out4, n4);
    } else {
        bilerp_direct<<<grid, block, 0, stream>>>(pts4, zs, out4, n4);
    }
}

// Round 6
// 109.692 us; speedup vs baseline: 1.4650x; 1.0605x over previous
//
#include <hip/hip_runtime.h>

#define GRID_NX 4096
#define GRID_NY 4096
#define PPT 4
#define PACK_ROWS 8

// Two-pass bilinear interp on uniform unit grid (xs=ys=arange).
//   searchsorted(arange,x,'left') == ceil(x), clipped to [1,4095]; dx=1 so
//   wx = x - x0 exactly.
// Pass 1: repack zs into bf16 vertical-pair table zp[i][j] = {bf16 z[i][j],
//   bf16 z[i+1][j]} (u32). 8 output rows/thread so each zs row is loaded
//   ~once (reads 72 MB vs 128 MB naive).
// Pass 2: one random 8 B load per point (cols iy-1, iy of row-pair ix-1)
//   -> exactly ONE 64 B line per point. Rounds 1-4 established the ceiling
//   is random-line fill traffic at ~3.4 TB/s; FETCH_SIZE 525->272 MB gave a
//   proportional 160->86 us. Streaming pts/out use non-temporal ops to keep
//   table lines resident in L2.

typedef float f32x4 __attribute__((ext_vector_type(4)));  // native vec for nontemporal builtins

__device__ __forceinline__ unsigned int bf16rn(float f) {
    unsigned int v = __builtin_bit_cast(unsigned int, f);
    return (v + 0x7fffu + ((v >> 16) & 1u)) >> 16;   // round-nearest-even
}
__device__ __forceinline__ float bf16lo_f(unsigned int u) {
    return __builtin_bit_cast(float, u << 16);
}
__device__ __forceinline__ float bf16hi_f(unsigned int u) {
    return __builtin_bit_cast(float, u & 0xffff0000u);
}

__global__ __launch_bounds__(256) void pack_kernel8(
    const float* __restrict__ zs,
    unsigned int* __restrict__ zp)   // (GRID_NX-1) x GRID_NY u32
{
    const int groups_per_row = GRID_NY / 4;          // 1024
    int t = blockIdx.x * blockDim.x + threadIdx.x;
    int g = t % groups_per_row;
    int tile = t / groups_per_row;
    int r0 = tile * PACK_ROWS;
    if (r0 >= GRID_NX - 1) return;

    const float* src = zs + 4 * (size_t)g;
    unsigned int* dst = zp + 4 * (size_t)g;

    float4 prev = *reinterpret_cast<const float4*>(src + (size_t)r0 * GRID_NY);
#pragma unroll
    for (int dr = 0; dr < PACK_ROWS; ++dr) {
        int r = r0 + dr;
        if (r < GRID_NX - 1) {
            float4 cur = *reinterpret_cast<const float4*>(src + (size_t)(r + 1) * GRID_NY);
            uint4 o;
            o.x = bf16rn(prev.x) | (bf16rn(cur.x) << 16);
            o.y = bf16rn(prev.y) | (bf16rn(cur.y) << 16);
            o.z = bf16rn(prev.z) | (bf16rn(cur.z) << 16);
            o.w = bf16rn(prev.w) | (bf16rn(cur.w) << 16);
            *reinterpret_cast<uint4*>(dst + (size_t)r * GRID_NY) = o;
            prev = cur;
        }
    }
}

__global__ __launch_bounds__(256) void bilerp_packed(
    const f32x4* __restrict__ pts4,
    const unsigned int* __restrict__ zp,
    f32x4* __restrict__ out4,
    int n4)
{
    int t = blockIdx.x * blockDim.x + threadIdx.x;
    if (t >= n4) return;

    f32x4 a = __builtin_nontemporal_load(&pts4[2 * t]);
    f32x4 b = __builtin_nontemporal_load(&pts4[2 * t + 1]);
    float x[PPT] = {a.x, a.z, b.x, b.z};
    float y[PPT] = {a.y, a.w, b.y, b.w};

    uint2 q[PPT];
    float wx[PPT], wy[PPT];
#pragma unroll
    for (int k = 0; k < PPT; ++k) {
        int ix = (int)ceilf(x[k]);
        int iy = (int)ceilf(y[k]);
        ix = min(max(ix, 1), GRID_NX - 1);
        iy = min(max(iy, 1), GRID_NY - 1);
        wx[k] = x[k] - (float)(ix - 1);
        wy[k] = y[k] - (float)(iy - 1);
        q[k] = *reinterpret_cast<const uint2*>(zp + (size_t)(ix - 1) * GRID_NY + (iy - 1));
    }

    f32x4 r;
#pragma unroll
    for (int k = 0; k < PPT; ++k) {
        float z00 = bf16lo_f(q[k].x), z10 = bf16hi_f(q[k].x);
        float z01 = bf16lo_f(q[k].y), z11 = bf16hi_f(q[k].y);
        float r0 = (1.0f - wy[k]) * z00 + wy[k] * z01;
        float r1 = (1.0f - wy[k]) * z10 + wy[k] * z11;
        r[k] = (1.0f - wx[k]) * r0 + wx[k] * r1;
    }
    __builtin_nontemporal_store(r, &out4[t]);
}

// Fallback if workspace is too small for the table.
__global__ __launch_bounds__(256) void bilerp_direct(
    const float4* __restrict__ pts4,
    const float* __restrict__ zs,
    float4* __restrict__ out4,
    int n4)
{
    int t = blockIdx.x * blockDim.x + threadIdx.x;
    if (t >= n4) return;
    float4 a = pts4[2 * t];
    float4 b = pts4[2 * t + 1];
    float x[PPT] = {a.x, a.z, b.x, b.z};
    float y[PPT] = {a.y, a.w, b.y, b.w};
    float2 lo[PPT], hi[PPT];
    float wx[PPT], wy[PPT];
#pragma unroll
    for (int k = 0; k < PPT; ++k) {
        int ix = (int)ceilf(x[k]);
        int iy = (int)ceilf(y[k]);
        ix = min(max(ix, 1), GRID_NX - 1);
        iy = min(max(iy, 1), GRID_NY - 1);
        wx[k] = x[k] - (float)(ix - 1);
        wy[k] = y[k] - (float)(iy - 1);
        const float* base = zs + (size_t)(ix - 1) * GRID_NY + (iy - 1);
        lo[k] = *reinterpret_cast<const float2*>(base);
        hi[k] = *reinterpret_cast<const float2*>(base + GRID_NY);
    }
    float4 r;
    float* rp = &r.x;
#pragma unroll
    for (int k = 0; k < PPT; ++k) {
        float r0 = (1.0f - wy[k]) * lo[k].x + wy[k] * lo[k].y;
        float r1 = (1.0f - wy[k]) * hi[k].x + wy[k] * hi[k].y;
        rp[k] = (1.0f - wx[k]) * r0 + wx[k] * r1;
    }
    out4[t] = r;
}

extern "C" void kernel_launch(void* const* d_in, const int* in_sizes, int n_in,
                              void* d_out, int out_size, void* d_ws, size_t ws_size,
                              hipStream_t stream) {
    const float* zs = (const float*)d_in[3];

    int n = in_sizes[0] / 2;
    int n4 = n / 4;
    int block = 256;
    int grid = (n4 + block - 1) / block;

    const size_t table_bytes = (size_t)(GRID_NX - 1) * GRID_NY * sizeof(unsigned int);
    if (ws_size >= table_bytes) {
        unsigned int* zp = (unsigned int*)d_ws;
        int row_tiles = (GRID_NX - 1 + PACK_ROWS - 1) / PACK_ROWS;   // 512
        int pack_threads = row_tiles * (GRID_NY / 4);
        int pack_grid = (pack_threads + block - 1) / block;
        pack_kernel8<<<pack_grid, block, 0, stream>>>(zs, zp);
        bilerp_packed<<<grid, block, 0, stream>>>((const f32x4*)d_in[0], zp,
                                                  (f32x4*)d_out, n4);
    } else {
        bilerp_direct<<<grid, block, 0, stream>>>((const float4*)d_in[0], zs,
                                                  (float4*)d_out, n4);
    }
}